// Round 8
// baseline (2239.005 us; speedup 1.0000x reference)
//
#include <hip/hip_runtime.h>
#include <hip/hip_bf16.h>
#include <math.h>

#define KIMG 8
#define HH 128
#define WW 128
#define NTOK (HH*WW)
#define DD 768
#define CC 10
#define NITER 5
#define GA 32          // assign blocks per image -> 256 blocks total = 1/CU
#define WVS 8          // waves per assign block (512 threads)

// ---------- wave helpers ----------
__device__ __forceinline__ float rl_f(float x, int l){
  return __int_as_float(__builtin_amdgcn_readlane(__float_as_int(x), l));
}
__device__ __forceinline__ float rfl_f(float x){
  return __int_as_float(__builtin_amdgcn_readfirstlane(__float_as_int(x)));
}
template<int CTRL,int RMASK>
__device__ __forceinline__ float dppadd(float x){
  // compiler-managed DPP (hazard-safe): mov_dpp + add
  int y = __builtin_amdgcn_update_dpp(0, __float_as_int(x), CTRL, RMASK, 0xf, true);
  return x + __int_as_float(y);
}
// sum across a 4-lane quad (2-step butterfly); result identical in all 4 lanes
__device__ __forceinline__ float quadred(float x){
  x = dppadd<0xB1,0xf>(x);   // quad_perm [1,0,3,2]
  x = dppadd<0x4E,0xf>(x);   // quad_perm [2,3,0,1]
  return x;
}
// full-wave sum; total lands in lane 63 (used by scalar_kernel only)
__device__ __forceinline__ float wredsum(float x){
  x = dppadd<0x111,0xf>(x);
  x = dppadd<0x112,0xf>(x);
  x = dppadd<0x114,0xf>(x);
  x = dppadd<0x118,0xf>(x);
  x = dppadd<0x142,0xa>(x);
  x = dppadd<0x143,0xc>(x);
  return x;
}
__device__ __forceinline__ float read_dim_f(const int* p){
  int v = *p;
  if (v > 0 && v < (1<<20)) return (float)v;   // plausible integer
  return __int_as_float(v);                    // else float bits
}

union F4 { float4 v; float f[4]; };

// ---------- 1. compact valid token indices (deterministic order) ----------
__global__ __launch_bounds__(256) void compact_kernel(const float* __restrict__ mask,
    int* __restrict__ vidx, int* __restrict__ vcnt){
  int k = blockIdx.x, tid = threadIdx.x;
  __shared__ int s[256];
  const float* mk = mask + (size_t)k*NTOK;
  int base = tid*64, c = 0;
  for (int j=0;j<64;j++) c += (mk[base+j] > 0.f) ? 1 : 0;
  s[tid] = c; __syncthreads();
  for (int st=1; st<256; st<<=1){
    int v = s[tid]; int u = (tid>=st) ? s[tid-st] : 0;
    __syncthreads(); s[tid] = v+u; __syncthreads();
  }
  int off = s[tid] - c;          // exclusive prefix
  if (tid==255) vcnt[k] = s[255];
  int* vk = vidx + (size_t)k*NTOK;
  for (int j=0;j<64;j++){ if (mk[base+j] > 0.f) vk[off++] = base+j; }
}

// ---------- 2. initial centroids = tokens[init_idx] ----------
__global__ __launch_bounds__(256) void init_kernel(const float* __restrict__ feat,
  const float* __restrict__ boxes, const float* __restrict__ Wp, const float* __restrict__ bp,
  const int* __restrict__ iidx, const int* __restrict__ prawh, const int* __restrict__ praww,
  float* __restrict__ cent){
  int k = blockIdx.x, tid = threadIdx.x;
  float top = boxes[k*4+0], lft = boxes[k*4+1], bot = boxes[k*4+2], rgt = boxes[k*4+3];
  float rh = read_dim_f(prawh), rw = read_dim_f(praww);
  float inv_rw = 1.f/(rw-1.f), inv_rh = 1.f/(rh-1.f);
  float xs = (rgt-lft)*(1.f/(float)WW), ys = (bot-top)*(1.f/(float)HH);
  for (int c=0;c<CC;c++){
    int tok = iidx[k*CC+c];
    int h = tok>>7, w = tok&127;
    float xg = fminf(fmaxf(((float)w*xs+lft)*inv_rw,0.f),1.f);
    float yg = fminf(fmaxf(((float)h*ys+top)*inv_rh,0.f),1.f);
    const float* fp = feat + ((size_t)k*NTOK + tok)*DD;
    float* cp = cent + ((size_t)k*CC + c)*DD;
    for (int d=tid; d<DD; d+=256)
      cp[d] = fp[d] + xg*Wp[d] + yg*Wp[DD+d] + bp[d];
  }
}

// ---------- 2b. per-cluster scalars: sA=||c||^2-2bp.c, sW0=-2Wp0.c, sW1=-2Wp1.c ----------
__global__ __launch_bounds__(64) void scalar_kernel(const float* __restrict__ cent,
  const float* __restrict__ Wp, const float* __restrict__ bp, float* __restrict__ scal){
  int c = blockIdx.x, k = blockIdx.y, lane = threadIdx.x;
  const float* cp = cent + ((size_t)k*CC+c)*DD;
  float a0=0.f,a1=0.f,ab=0.f,an=0.f;
  #pragma unroll
  for (int j=0;j<12;j++){
    float cv = cp[j*64+lane];
    a0=fmaf(cv,Wp[j*64+lane],a0);
    a1=fmaf(cv,Wp[DD+j*64+lane],a1);
    ab=fmaf(cv,bp[j*64+lane],ab);
    an=fmaf(cv,cv,an);
  }
  a0=wredsum(a0); a1=wredsum(a1); ab=wredsum(ab); an=wredsum(an);
  if (lane==63){
    float* o = scal + ((size_t)k*CC+c)*4;
    o[0]=fmaf(-2.f,ab,an); o[1]=-2.f*a0; o[2]=-2.f*a1; o[3]=0.f;
  }
}

// ---------- 3. assignment + per-block partial sums (hot) ----------
// Quad-owns-token: 4 consecutive lanes share one token; lane (quad q, part r4)
// covers dims {r4*4 + m + 16*ch}. Per chunk instruction the wave reads 16 full
// 64B cache lines (pure streaming, each line touched once). Dots reduced by a
// 2-step quad_perm butterfly (40 independent short chains -- no long DPP
// dependency chains). Centroids from LDS as 4 addresses x16-way broadcast.
// One 64-token superbatch per wave (mycnt <= 64 by construction).
__global__ __launch_bounds__(512,2) void assign_kernel(
    const float* __restrict__ feat, const float* __restrict__ boxes,
    const int* __restrict__ prawh, const int* __restrict__ praww,
    const float* __restrict__ cent, const float* __restrict__ scal,
    const int* __restrict__ vidx, const int* __restrict__ vcnt,
    float* __restrict__ fsums, float* __restrict__ osxg, float* __restrict__ osyg,
    int* __restrict__ ocnt)
{
  int g = blockIdx.x, k = blockIdx.y;
  int tid = threadIdx.x, lane = tid & 63, wv = tid >> 6;
  __shared__ float s_cent[CC*DD];           // -2 * centroids
  __shared__ float s_sums[CC*DD];           // physical p = jj*256 + m*64 + lane
  __shared__ float s_sxg[16], s_syg[16];
  __shared__ int   s_cnt[16];
  const float* ck = cent + (size_t)k*CC*DD;
  for (int x=tid;x<CC*DD;x+=512){ s_cent[x] = -2.f*ck[x]; s_sums[x]=0.f; }
  if (tid<16){ s_sxg[tid]=0.f; s_syg[tid]=0.f; s_cnt[tid]=0; }
  __syncthreads();

  // per-cluster scalars -> SGPRs (wave-uniform)
  float sA[CC], sW0[CC], sW1[CC];
  #pragma unroll
  for (int c=0;c<CC;c++){
    F4 sv; sv.v = *(const float4*)(scal + ((size_t)k*CC+c)*4);
    sA[c]=rfl_f(sv.f[0]); sW0[c]=rfl_f(sv.f[1]); sW1[c]=rfl_f(sv.f[2]);
  }

  float top=rfl_f(boxes[k*4+0]), lft=rfl_f(boxes[k*4+1]);
  float bot=rfl_f(boxes[k*4+2]), rgt=rfl_f(boxes[k*4+3]);
  float rh = read_dim_f(prawh), rw = read_dim_f(praww);
  float inv_rw = 1.f/(rw-1.f), inv_rh = 1.f/(rh-1.f);
  float xs = (rgt-lft)*(1.f/(float)WW), ys = (bot-top)*(1.f/(float)HH);

  int count = vcnt[k];
  int nw = GA*WVS;                          // 256 waves per image
  int wid = g*WVS + wv;
  int cbeg = (int)(((long long)count * wid) / nw);
  int cend = (int)(((long long)count * (wid+1)) / nw);
  int mycnt = cend - cbeg;                  // <= 64 (one superbatch)
  const int* vk = vidx + (size_t)k*NTOK;
  const float* featk = feat + (size_t)k*NTOK*DD;
  int c1 = count - 1;

  if (mycnt > 0){
    int q  = lane >> 2;                     // token slot within 16
    int r4 = lane & 3;                      // dim part
    int vvt = vk[min(cbeg + lane, c1)];     // lane-held token ids (for sum phase)

    // 4 token groups of 16 -> lane owns 4 tokens (one per group)
    const float* rb[4]; float xg[4], yg[4];
    #pragma unroll
    for (int b=0;b<4;b++){
      int o = min(b*16 + q, mycnt-1);
      int t = vk[min(cbeg + o, c1)];
      rb[b] = featk + (size_t)t*DD + r4*4;
      xg[b] = fminf(fmaxf(((float)(t&127)*xs+lft)*inv_rw,0.f),1.f);
      yg[b] = fminf(fmaxf(((float)(t>>7) *ys+top)*inv_rh,0.f),1.f);
    }

    float acc[4][CC];
    #pragma unroll
    for (int b=0;b<4;b++)
      #pragma unroll
      for (int c=0;c<CC;c++) acc[b][c]=0.f;

    for (int ch=0; ch<48; ++ch){            // 48 x 16 dims = 768
      F4 tf[4];
      #pragma unroll
      for (int b=0;b<4;b++) tf[b].v = *(const float4*)(rb[b] + ch*16);
      #pragma unroll
      for (int c=0;c<CC;c++){
        F4 cs; cs.v = *(const float4*)(s_cent + c*DD + ch*16 + r4*4);
        #pragma unroll
        for (int b=0;b<4;b++)
          #pragma unroll
          for (int m=0;m<4;m++)
            acc[b][c] = fmaf(tf[b].f[m], cs.f[m], acc[b][c]);
      }
    }

    // quad butterfly (40 independent 2-step chains) + per-token argmin
    int bl[4];
    #pragma unroll
    for (int b=0;b<4;b++){
      float best=3.4e38f; int bb=0;
      #pragma unroll
      for (int c=0;c<CC;c++){
        float d = quadred(acc[b][c]);       // = -2*(t.c), same in all 4 quad lanes
        float sc = fmaf(xg[b],sW0[c], fmaf(yg[b],sW1[c], sA[c])) + d;
        if (sc < best){ best=sc; bb=c; }
      }
      bl[b]=bb;
    }

    // sum phase: per token, 64 lanes cooperatively add 12 dims each (coalesced
    // re-read, L2/L3-hot). Depth-1 data prefetch; labels via uniform readlane.
    {
      int tk0 = __builtin_amdgcn_readlane(vvt, 0);
      const float* fp = featk + (size_t)tk0*DD + 4*lane;
      F4 A0,A1,A2;
      A0.v=*(const float4*)(fp); A1.v=*(const float4*)(fp+256); A2.v=*(const float4*)(fp+512);
      for (int tt=0; tt<mycnt; ++tt){
        int tn = __builtin_amdgcn_readlane(vvt, min(tt+1, mycnt-1));
        const float* fq = featk + (size_t)tn*DD + 4*lane;
        F4 N0,N1,N2;
        N0.v=*(const float4*)(fq); N1.v=*(const float4*)(fq+256); N2.v=*(const float4*)(fq+512);

        int b = tt>>4, src = (tt&15)*4;     // b is wave-uniform; static indexing only
        int bsel; float xgs, ygs;
        if      (b==0){ bsel=__builtin_amdgcn_readlane(bl[0],src); xgs=rl_f(xg[0],src); ygs=rl_f(yg[0],src); }
        else if (b==1){ bsel=__builtin_amdgcn_readlane(bl[1],src); xgs=rl_f(xg[1],src); ygs=rl_f(yg[1],src); }
        else if (b==2){ bsel=__builtin_amdgcn_readlane(bl[2],src); xgs=rl_f(xg[2],src); ygs=rl_f(yg[2],src); }
        else          { bsel=__builtin_amdgcn_readlane(bl[3],src); xgs=rl_f(xg[3],src); ygs=rl_f(yg[3],src); }

        float* sb = s_sums + bsel*DD + lane;  // physical p = jj*256+m*64+lane
        atomicAdd(&sb[  0], A0.f[0]); atomicAdd(&sb[ 64], A0.f[1]);
        atomicAdd(&sb[128], A0.f[2]); atomicAdd(&sb[192], A0.f[3]);
        atomicAdd(&sb[256], A1.f[0]); atomicAdd(&sb[320], A1.f[1]);
        atomicAdd(&sb[384], A1.f[2]); atomicAdd(&sb[448], A1.f[3]);
        atomicAdd(&sb[512], A2.f[0]); atomicAdd(&sb[576], A2.f[1]);
        atomicAdd(&sb[640], A2.f[2]); atomicAdd(&sb[704], A2.f[3]);
        if (lane==0){
          atomicAdd(&s_cnt[bsel],1);
          atomicAdd(&s_sxg[bsel],xgs);
          atomicAdd(&s_syg[bsel],ygs);
        }
        A0=N0; A1=N1; A2=N2;
      }
    }
  }
  __syncthreads();

  float* fo = fsums + ((size_t)(k*GA+g))*CC*DD;
  for (int x=tid;x<CC*DD;x+=512) fo[x]=s_sums[x];
  if (tid<CC){
    size_t o = (size_t)(k*GA+g)*CC + tid;
    osxg[o]=s_sxg[tid]; osyg[o]=s_syg[tid]; ocnt[o]=s_cnt[tid];
  }
}

// ---------- 4. deterministic reduce over GA partials + centroid update ----------
// fsums physical p = jj*256 + m*64 + l ; logical d = 256*jj + 4*l + m
__global__ __launch_bounds__(256) void update_kernel(
  const float* __restrict__ fsums, const float* __restrict__ osxg, const float* __restrict__ osyg,
  const int* __restrict__ ocnt, const float* __restrict__ Wp, const float* __restrict__ bp,
  float* __restrict__ cent)
{
  int idx = blockIdx.x*256 + threadIdx.x;   // over K*C*D ; (k,c) uniform per block
  int d  = idx % DD;
  int kc = idx / DD;
  int k  = kc / CC, c = kc % CC;
  int j = d >> 8, r = d & 255, l = r >> 2, m = r & 3;
  int p = (j << 8) | (m << 6) | l;
  __shared__ float sX[GA], sY[GA]; __shared__ int sN[GA];
  if (threadIdx.x < GA){
    int g = threadIdx.x;
    size_t o = (size_t)(k*GA+g)*CC + c;
    sX[g]=osxg[o]; sY[g]=osyg[o]; sN[g]=ocnt[o];
  }
  __syncthreads();
  int n=0; float sx=0.f, sy=0.f;
  for (int t=0;t<GA;t++){ n+=sN[t]; sx+=sX[t]; sy+=sY[t]; }
  float s=0.f;
  for (int g=0; g<GA; g++)
    s += fsums[((size_t)(k*GA+g)*CC + c)*DD + p];
  if (n > 0){
    float nf = (float)n;
    float ts = s + sx*Wp[d] + sy*Wp[DD+d] + nf*bp[d];  // factored posenc re-applied
    cent[(size_t)kc*DD + d] = ts / nf;
  } // else keep old centroid
}

// ---------- 5. MLP ----------
__global__ __launch_bounds__(256) void mlp1_kernel(const float* __restrict__ cent,
  const float* __restrict__ W1, const float* __restrict__ b1, float* __restrict__ h1)
{
  int k = blockIdx.y; int col = blockIdx.x*256 + threadIdx.x;
  __shared__ float srow[CC*DD];
  for (int x=threadIdx.x; x<CC*DD; x+=256) srow[x] = cent[(size_t)k*CC*DD + x];
  __syncthreads();
  float acc[CC];
  #pragma unroll
  for (int r=0;r<CC;r++) acc[r]=0.f;
  for (int dd=0; dd<DD; dd++){
    float wv = W1[(size_t)dd*DD + col];
    #pragma unroll
    for (int r=0;r<CC;r++) acc[r] = fmaf(srow[r*DD+dd], wv, acc[r]);
  }
  float bb = b1[col];
  #pragma unroll
  for (int r=0;r<CC;r++){
    float x = acc[r] + bb;
    h1[((size_t)k*CC+r)*DD + col] = 0.5f*x*(1.f+erff(x*0.70710678118654752440f));
  }
}

__global__ __launch_bounds__(256) void mlp2_kernel(const float* __restrict__ h1,
  const float* __restrict__ W2, const float* __restrict__ b2, float* __restrict__ out)
{
  int k = blockIdx.y; int col = blockIdx.x*256 + threadIdx.x;
  __shared__ float srow[CC*DD];
  for (int x=threadIdx.x; x<CC*DD; x+=256) srow[x] = h1[(size_t)k*CC*DD + x];
  __syncthreads();
  float acc[CC];
  #pragma unroll
  for (int r=0;r<CC;r++) acc[r]=0.f;
  for (int dd=0; dd<DD; dd++){
    float wv = W2[(size_t)dd*DD + col];
    #pragma unroll
    for (int r=0;r<CC;r++) acc[r] = fmaf(srow[r*DD+dd], wv, acc[r]);
  }
  float bb2 = b2[col];
  #pragma unroll
  for (int r=0;r<CC;r++) out[((size_t)k*CC+r)*DD + col] = acc[r] + bb2;
}

// ---------- launch ----------
extern "C" void kernel_launch(void* const* d_in, const int* in_sizes, int n_in,
                              void* d_out, int out_size, void* d_ws, size_t ws_size,
                              hipStream_t stream)
{
  const float* feat = (const float*)d_in[0];
  const float* mask = (const float*)d_in[1];
  const float* boxes= (const float*)d_in[2];
  const float* Wp   = (const float*)d_in[3];
  const float* bp   = (const float*)d_in[4];
  const float* W1   = (const float*)d_in[5];
  const float* b1   = (const float*)d_in[6];
  const float* W2   = (const float*)d_in[7];
  const float* b2   = (const float*)d_in[8];
  const int*   iidx = (const int*)d_in[9];
  const int*   prawh= (const int*)d_in[10];
  const int*   praww= (const int*)d_in[11];
  float* out = (float*)d_out;

  auto align = [](size_t x){ return (x + 255) & ~(size_t)255; };
  size_t off = 0;
  size_t o_cent = off; off = align(off + (size_t)KIMG*CC*DD*4);
  size_t o_vidx = off; off = align(off + (size_t)KIMG*NTOK*4);
  size_t o_vcnt = off; off = align(off + (size_t)KIMG*4);
  size_t o_scal = off; off = align(off + (size_t)KIMG*CC*4*4);
  size_t o_h1   = off; off = align(off + (size_t)KIMG*CC*DD*4);
  size_t o_fs   = off; off = align(off + (size_t)KIMG*GA*CC*DD*4);
  size_t o_sx   = off; off = align(off + (size_t)KIMG*GA*CC*4);
  size_t o_sy   = off; off = align(off + (size_t)KIMG*GA*CC*4);
  size_t o_cn   = off; off = align(off + (size_t)KIMG*GA*CC*4);
  (void)ws_size;  // ~10.3 MB needed; prior rounds confirm ws_size is larger

  char* ws = (char*)d_ws;
  float* cent  = (float*)(ws + o_cent);
  int*   vidx  = (int*)  (ws + o_vidx);
  int*   vcnt  = (int*)  (ws + o_vcnt);
  float* scal  = (float*)(ws + o_scal);
  float* h1    = (float*)(ws + o_h1);
  float* fsums = (float*)(ws + o_fs);
  float* sxg   = (float*)(ws + o_sx);
  float* syg   = (float*)(ws + o_sy);
  int*   ocnt  = (int*)  (ws + o_cn);

  compact_kernel<<<KIMG,256,0,stream>>>(mask, vidx, vcnt);
  init_kernel<<<KIMG,256,0,stream>>>(feat, boxes, Wp, bp, iidx, prawh, praww, cent);
  scalar_kernel<<<dim3(CC,KIMG),64,0,stream>>>(cent, Wp, bp, scal);
  for (int it=0; it<NITER; ++it){
    assign_kernel<<<dim3(GA,KIMG),512,0,stream>>>(feat, boxes, prawh, praww,
        cent, scal, vidx, vcnt, fsums, sxg, syg, ocnt);
    update_kernel<<<(KIMG*CC*DD)/256,256,0,stream>>>(fsums, sxg, syg, ocnt, Wp, bp, cent);
    if (it < NITER-1)
      scalar_kernel<<<dim3(CC,KIMG),64,0,stream>>>(cent, Wp, bp, scal);
  }
  mlp1_kernel<<<dim3(3,KIMG),256,0,stream>>>(cent, W1, b1, h1);
  mlp2_kernel<<<dim3(3,KIMG),256,0,stream>>>(h1, W2, b2, out);
}

// Round 9
// 708.192 us; speedup vs baseline: 3.1616x; 3.1616x over previous
//
#include <hip/hip_runtime.h>
#include <hip/hip_bf16.h>
#include <math.h>

#define KIMG 8
#define HH 128
#define WW 128
#define NTOK (HH*WW)
#define DD 768
#define CC 10
#define NITER 5
#define GA 32          // assign blocks per image (256 total)
#define TG 32          // sum tokgroups per image
#define WVS 8          // waves per block (512 threads)
#define NWV (GA*WVS)   // 256 waves per image (both A and B partitions)

// ---------- wave helpers ----------
__device__ __forceinline__ float rl_f(float x, int l){
  return __int_as_float(__builtin_amdgcn_readlane(__float_as_int(x), l));
}
__device__ __forceinline__ float rfl_f(float x){
  return __int_as_float(__builtin_amdgcn_readfirstlane(__float_as_int(x)));
}
template<int CTRL,int RMASK>
__device__ __forceinline__ float dppadd(float x){
  // compiler-managed DPP (hazard-safe): mov_dpp + add
  int y = __builtin_amdgcn_update_dpp(0, __float_as_int(x), CTRL, RMASK, 0xf, true);
  return x + __int_as_float(y);
}
// sum across a 4-lane quad; result identical in all 4 lanes
__device__ __forceinline__ float quadred(float x){
  x = dppadd<0xB1,0xf>(x);   // quad_perm [1,0,3,2]
  x = dppadd<0x4E,0xf>(x);   // quad_perm [2,3,0,1]
  return x;
}
// full-wave sum; total lands in lane 63
__device__ __forceinline__ float wredsum(float x){
  x = dppadd<0x111,0xf>(x);
  x = dppadd<0x112,0xf>(x);
  x = dppadd<0x114,0xf>(x);
  x = dppadd<0x118,0xf>(x);
  x = dppadd<0x142,0xa>(x);
  x = dppadd<0x143,0xc>(x);
  return x;
}
__device__ __forceinline__ float read_dim_f(const int* p){
  int v = *p;
  if (v > 0 && v < (1<<20)) return (float)v;   // plausible integer
  return __int_as_float(v);                    // else float bits
}

union F4 { float4 v; float f[4]; };

// ---------- 1. compact valid token indices (deterministic order) ----------
__global__ __launch_bounds__(256) void compact_kernel(const float* __restrict__ mask,
    int* __restrict__ vidx, int* __restrict__ vcnt){
  int k = blockIdx.x, tid = threadIdx.x;
  __shared__ int s[256];
  const float* mk = mask + (size_t)k*NTOK;
  int base = tid*64, c = 0;
  for (int j=0;j<64;j++) c += (mk[base+j] > 0.f) ? 1 : 0;
  s[tid] = c; __syncthreads();
  for (int st=1; st<256; st<<=1){
    int v = s[tid]; int u = (tid>=st) ? s[tid-st] : 0;
    __syncthreads(); s[tid] = v+u; __syncthreads();
  }
  int off = s[tid] - c;          // exclusive prefix
  if (tid==255) vcnt[k] = s[255];
  int* vk = vidx + (size_t)k*NTOK;
  for (int j=0;j<64;j++){ if (mk[base+j] > 0.f) vk[off++] = base+j; }
}

// ---------- 2. initial centroids = tokens[init_idx] ----------
__global__ __launch_bounds__(256) void init_kernel(const float* __restrict__ feat,
  const float* __restrict__ boxes, const float* __restrict__ Wp, const float* __restrict__ bp,
  const int* __restrict__ iidx, const int* __restrict__ prawh, const int* __restrict__ praww,
  float* __restrict__ cent){
  int k = blockIdx.x, tid = threadIdx.x;
  float top = boxes[k*4+0], lft = boxes[k*4+1], bot = boxes[k*4+2], rgt = boxes[k*4+3];
  float rh = read_dim_f(prawh), rw = read_dim_f(praww);
  float inv_rw = 1.f/(rw-1.f), inv_rh = 1.f/(rh-1.f);
  float xs = (rgt-lft)*(1.f/(float)WW), ys = (bot-top)*(1.f/(float)HH);
  for (int c=0;c<CC;c++){
    int tok = iidx[k*CC+c];
    int h = tok>>7, w = tok&127;
    float xg = fminf(fmaxf(((float)w*xs+lft)*inv_rw,0.f),1.f);
    float yg = fminf(fmaxf(((float)h*ys+top)*inv_rh,0.f),1.f);
    const float* fp = feat + ((size_t)k*NTOK + tok)*DD;
    float* cp = cent + ((size_t)k*CC + c)*DD;
    for (int d=tid; d<DD; d+=256)
      cp[d] = fp[d] + xg*Wp[d] + yg*Wp[DD+d] + bp[d];
  }
}

// ---------- 2b. per-cluster scalars: sA=||c||^2-2bp.c, sW0=-2Wp0.c, sW1=-2Wp1.c ----------
__global__ __launch_bounds__(64) void scalar_kernel(const float* __restrict__ cent,
  const float* __restrict__ Wp, const float* __restrict__ bp, float* __restrict__ scal){
  int c = blockIdx.x, k = blockIdx.y, lane = threadIdx.x;
  const float* cp = cent + ((size_t)k*CC+c)*DD;
  float a0=0.f,a1=0.f,ab=0.f,an=0.f;
  #pragma unroll
  for (int j=0;j<12;j++){
    float cv = cp[j*64+lane];
    a0=fmaf(cv,Wp[j*64+lane],a0);
    a1=fmaf(cv,Wp[DD+j*64+lane],a1);
    ab=fmaf(cv,bp[j*64+lane],ab);
    an=fmaf(cv,cv,an);
  }
  a0=wredsum(a0); a1=wredsum(a1); ab=wredsum(ab); an=wredsum(an);
  if (lane==63){
    float* o = scal + ((size_t)k*CC+c)*4;
    o[0]=fmaf(-2.f,ab,an); o[1]=-2.f*a0; o[2]=-2.f*a1; o[3]=0.f;
  }
}

// ---------- 3a. LABELS: streaming dot phase, NO LDS atomics ----------
// Quad-owns-token (r8 dot structure). Outputs: labels[token] (plain stores)
// and per-wave aux (cnt/sxg/syg) reduced in registers + one wredsum per wave.
__global__ __launch_bounds__(512) void assign_kernel(
    const float* __restrict__ feat, const float* __restrict__ boxes,
    const int* __restrict__ prawh, const int* __restrict__ praww,
    const float* __restrict__ cent, const float* __restrict__ scal,
    const int* __restrict__ vidx, const int* __restrict__ vcnt,
    int* __restrict__ labels, float* __restrict__ osxg, float* __restrict__ osyg,
    float* __restrict__ ocnt)
{
  int g = blockIdx.x, k = blockIdx.y;
  int tid = threadIdx.x, lane = tid & 63, wv = tid >> 6;
  __shared__ float s_cent[CC*DD];           // -2 * centroids
  const float* ck = cent + (size_t)k*CC*DD;
  for (int x=tid;x<CC*DD;x+=512) s_cent[x] = -2.f*ck[x];
  __syncthreads();

  // per-cluster scalars -> SGPRs (wave-uniform)
  float sA[CC], sW0[CC], sW1[CC];
  #pragma unroll
  for (int c=0;c<CC;c++){
    F4 sv; sv.v = *(const float4*)(scal + ((size_t)k*CC+c)*4);
    sA[c]=rfl_f(sv.f[0]); sW0[c]=rfl_f(sv.f[1]); sW1[c]=rfl_f(sv.f[2]);
  }

  float top=rfl_f(boxes[k*4+0]), lft=rfl_f(boxes[k*4+1]);
  float bot=rfl_f(boxes[k*4+2]), rgt=rfl_f(boxes[k*4+3]);
  float rh = read_dim_f(prawh), rw = read_dim_f(praww);
  float inv_rw = 1.f/(rw-1.f), inv_rh = 1.f/(rh-1.f);
  float xs = (rgt-lft)*(1.f/(float)WW), ys = (bot-top)*(1.f/(float)HH);

  int count = vcnt[k];
  int wid = g*WVS + wv;                     // 0..255
  int cbeg = (int)(((long long)count * wid) / NWV);
  int cend = (int)(((long long)count * (wid+1)) / NWV);
  int mycnt = cend - cbeg;                  // <= 64
  const int* vk = vidx + (size_t)k*NTOK;
  const float* featk = feat + (size_t)k*NTOK*DD;
  int* lk = labels + (size_t)k*NTOK;
  int c1 = count - 1;

  float axc[CC], axx[CC], axy[CC];
  #pragma unroll
  for (int c=0;c<CC;c++){ axc[c]=0.f; axx[c]=0.f; axy[c]=0.f; }

  if (mycnt > 0){
    int q  = lane >> 2;                     // token slot within 16
    int r4 = lane & 3;                      // dim part

    const float* rb[4]; float xg[4], yg[4];
    #pragma unroll
    for (int b=0;b<4;b++){
      int o = min(b*16 + q, mycnt-1);
      int t = vk[min(cbeg + o, c1)];
      rb[b] = featk + (size_t)t*DD + r4*4;
      xg[b] = fminf(fmaxf(((float)(t&127)*xs+lft)*inv_rw,0.f),1.f);
      yg[b] = fminf(fmaxf(((float)(t>>7) *ys+top)*inv_rh,0.f),1.f);
    }

    float acc[4][CC];
    #pragma unroll
    for (int b=0;b<4;b++)
      #pragma unroll
      for (int c=0;c<CC;c++) acc[b][c]=0.f;

    for (int ch=0; ch<48; ++ch){            // 48 x 16 dims = 768
      F4 tf[4];
      #pragma unroll
      for (int b=0;b<4;b++) tf[b].v = *(const float4*)(rb[b] + ch*16);
      #pragma unroll
      for (int c=0;c<CC;c++){
        F4 cs; cs.v = *(const float4*)(s_cent + c*DD + ch*16 + r4*4);
        #pragma unroll
        for (int b=0;b<4;b++)
          #pragma unroll
          for (int m=0;m<4;m++)
            acc[b][c] = fmaf(tf[b].f[m], cs.f[m], acc[b][c]);
      }
    }

    int bl[4];
    #pragma unroll
    for (int b=0;b<4;b++){
      float best=3.4e38f; int bb=0;
      #pragma unroll
      for (int c=0;c<CC;c++){
        float d = quadred(acc[b][c]);       // = -2*(t.c), same in all 4 quad lanes
        float sc = fmaf(xg[b],sW0[c], fmaf(yg[b],sW1[c], sA[c])) + d;
        if (sc < best){ best=sc; bb=c; }
      }
      bl[b]=bb;
    }

    // plain label stores (one lane per quad); clamped dupes store same value
    #pragma unroll
    for (int b=0;b<4;b++){
      if (r4==0) lk[cbeg + min(b*16 + q, mycnt-1)] = bl[b];
    }

    // register aux accumulate; each valid token counted by its 4 quad lanes
    #pragma unroll
    for (int b=0;b<4;b++){
      bool val = (b*16 + q) < mycnt;
      #pragma unroll
      for (int c=0;c<CC;c++){
        bool mm = val && (bl[b]==c);
        axc[c] += mm ? 1.f   : 0.f;
        axx[c] += mm ? xg[b] : 0.f;
        axy[c] += mm ? yg[b] : 0.f;
      }
    }
  }

  // wave-level reduce (x4 overcount -> exact *0.25) and store per-wave aux
  #pragma unroll
  for (int c=0;c<CC;c++){
    axc[c]=wredsum(axc[c]); axx[c]=wredsum(axx[c]); axy[c]=wredsum(axy[c]);
  }
  if (lane==63){
    size_t o = ((size_t)k*NWV + wid)*CC;
    #pragma unroll
    for (int c=0;c<CC;c++){
      ocnt[o+c]=0.25f*axc[c]; osxg[o+c]=0.25f*axx[c]; osyg[o+c]=0.25f*axy[c];
    }
  }
}

// ---------- 3b. SUMS: label-gathered dim-slice accumulation, NO atomics ----------
// Block = (tokgroup, dim-slice of 256, image). Lane owns 4 dims; 40 register
// accumulators selected by uniform label; per-wave private LDS flush + tree
// reduce (fixed order, deterministic).
__global__ __launch_bounds__(512) void sum_kernel(
    const float* __restrict__ feat, const int* __restrict__ vidx,
    const int* __restrict__ vcnt, const int* __restrict__ labels,
    float* __restrict__ fsums)
{
  int tg = blockIdx.x, sl = blockIdx.y, k = blockIdx.z;
  int tid = threadIdx.x, lane = tid & 63, wv = tid >> 6;
  __shared__ float s_red[WVS*CC*256];       // 80 KiB
  int count = vcnt[k];
  int wid = tg*WVS + wv;                    // 0..255
  int wbeg = (int)(((long long)count * wid) / NWV);
  int wend = (int)(((long long)count * (wid+1)) / NWV);
  int mycnt = wend - wbeg;                  // <= 64
  const float* featk = feat + (size_t)k*NTOK*DD + sl*256;
  const int* vk = vidx + (size_t)k*NTOK;
  const int* lk = labels + (size_t)k*NTOK;

  float acc[CC][4];
  #pragma unroll
  for (int c=0;c<CC;c++)
    #pragma unroll
    for (int j=0;j<4;j++) acc[c][j]=0.f;

  if (mycnt > 0){
    int c1 = count - 1;
    int vvt = vk[min(wbeg + lane, c1)];     // lane-held token ids
    int vlb = lk[min(wbeg + lane, c1)];     // lane-held labels

    F4 bA, bB;
    {
      int t0 = __builtin_amdgcn_readlane(vvt, 0);
      int t1 = __builtin_amdgcn_readlane(vvt, min(1, mycnt-1));
      bA.v = *(const float4*)(featk + (size_t)t0*DD + lane*4);
      bB.v = *(const float4*)(featk + (size_t)t1*DD + lane*4);
    }
    for (int t=0; t<mycnt; t+=2){
      // depth-2 prefetch (clamped indices; extra loads are L1-hot dupes)
      F4 nA, nB;
      {
        int ta = __builtin_amdgcn_readlane(vvt, min(t+2, mycnt-1));
        int tb = __builtin_amdgcn_readlane(vvt, min(t+3, mycnt-1));
        nA.v = *(const float4*)(featk + (size_t)ta*DD + lane*4);
        nB.v = *(const float4*)(featk + (size_t)tb*DD + lane*4);
      }
      {
        int lbl = __builtin_amdgcn_readlane(vlb, t);
        #pragma unroll
        for (int c=0;c<CC;c++){
          bool mm = (lbl==c);
          #pragma unroll
          for (int j=0;j<4;j++) acc[c][j] += mm ? bA.f[j] : 0.f;
        }
      }
      if (t+1 < mycnt){
        int lbl = __builtin_amdgcn_readlane(vlb, t+1);
        #pragma unroll
        for (int c=0;c<CC;c++){
          bool mm = (lbl==c);
          #pragma unroll
          for (int j=0;j<4;j++) acc[c][j] += mm ? bB.f[j] : 0.f;
        }
      }
      bA = nA; bB = nB;
    }
  }

  // per-wave flush to private LDS slice (no races), then fixed-order tree
  float* myred = s_red + wv*(CC*256);
  #pragma unroll
  for (int c=0;c<CC;c++){
    F4 u;
    #pragma unroll
    for (int j=0;j<4;j++) u.f[j]=acc[c][j];
    *(float4*)(myred + c*256 + lane*4) = u.v;
  }
  __syncthreads();
  for (int x=tid; x<CC*256; x+=512){
    float s = 0.f;
    #pragma unroll
    for (int w=0; w<WVS; w++) s += s_red[w*(CC*256) + x];
    int c = x >> 8, dm = x & 255;
    fsums[(((size_t)k*TG + tg)*CC + c)*DD + sl*256 + dm] = s;
  }
}

// ---------- 4. deterministic reduce + centroid update ----------
__global__ __launch_bounds__(256) void update_kernel(
  const float* __restrict__ fsums, const float* __restrict__ osxg, const float* __restrict__ osyg,
  const float* __restrict__ ocnt, const float* __restrict__ Wp, const float* __restrict__ bp,
  float* __restrict__ cent)
{
  int idx = blockIdx.x*256 + threadIdx.x;   // over K*C*D ; (k,c) uniform per block
  int d  = idx % DD;
  int kc = idx / DD;
  int k  = kc / CC, c = kc % CC;

  // aux: 256 wave slots, one per thread -> wave wredsum -> 4-way LDS combine
  size_t o = ((size_t)k*NWV + threadIdx.x)*CC + c;
  float pn = ocnt[o], px = osxg[o], py = osyg[o];
  float wn = wredsum(pn), wx = wredsum(px), wy = wredsum(py);
  __shared__ float rn[4], rx[4], ry[4];
  if ((threadIdx.x & 63) == 63){
    rn[threadIdx.x>>6]=wn; rx[threadIdx.x>>6]=wx; ry[threadIdx.x>>6]=wy;
  }
  __syncthreads();
  float n  = rn[0]+rn[1]+rn[2]+rn[3];
  float sx = rx[0]+rx[1]+rx[2]+rx[3];
  float sy = ry[0]+ry[1]+ry[2]+ry[3];

  float s = 0.f;
  for (int g=0; g<TG; g++)
    s += fsums[(((size_t)k*TG + g)*CC + c)*DD + d];
  if (n > 0.5f){
    float ts = s + sx*Wp[d] + sy*Wp[DD+d] + n*bp[d];  // factored posenc re-applied
    cent[(size_t)kc*DD + d] = ts / n;
  } // else keep old centroid
}

// ---------- 5. MLP ----------
__global__ __launch_bounds__(256) void mlp1_kernel(const float* __restrict__ cent,
  const float* __restrict__ W1, const float* __restrict__ b1, float* __restrict__ h1)
{
  int k = blockIdx.y; int col = blockIdx.x*256 + threadIdx.x;
  __shared__ float srow[CC*DD];
  for (int x=threadIdx.x; x<CC*DD; x+=256) srow[x] = cent[(size_t)k*CC*DD + x];
  __syncthreads();
  float acc[CC];
  #pragma unroll
  for (int r=0;r<CC;r++) acc[r]=0.f;
  for (int dd=0; dd<DD; dd++){
    float wv = W1[(size_t)dd*DD + col];
    #pragma unroll
    for (int r=0;r<CC;r++) acc[r] = fmaf(srow[r*DD+dd], wv, acc[r]);
  }
  float bb = b1[col];
  #pragma unroll
  for (int r=0;r<CC;r++){
    float x = acc[r] + bb;
    h1[((size_t)k*CC+r)*DD + col] = 0.5f*x*(1.f+erff(x*0.70710678118654752440f));
  }
}

__global__ __launch_bounds__(256) void mlp2_kernel(const float* __restrict__ h1,
  const float* __restrict__ W2, const float* __restrict__ b2, float* __restrict__ out)
{
  int k = blockIdx.y; int col = blockIdx.x*256 + threadIdx.x;
  __shared__ float srow[CC*DD];
  for (int x=threadIdx.x; x<CC*DD; x+=256) srow[x] = h1[(size_t)k*CC*DD + x];
  __syncthreads();
  float acc[CC];
  #pragma unroll
  for (int r=0;r<CC;r++) acc[r]=0.f;
  for (int dd=0; dd<DD; dd++){
    float wv = W2[(size_t)dd*DD + col];
    #pragma unroll
    for (int r=0;r<CC;r++) acc[r] = fmaf(srow[r*DD+dd], wv, acc[r]);
  }
  float bb2 = b2[col];
  #pragma unroll
  for (int r=0;r<CC;r++) out[((size_t)k*CC+r)*DD + col] = acc[r] + bb2;
}

// ---------- launch ----------
extern "C" void kernel_launch(void* const* d_in, const int* in_sizes, int n_in,
                              void* d_out, int out_size, void* d_ws, size_t ws_size,
                              hipStream_t stream)
{
  const float* feat = (const float*)d_in[0];
  const float* mask = (const float*)d_in[1];
  const float* boxes= (const float*)d_in[2];
  const float* Wp   = (const float*)d_in[3];
  const float* bp   = (const float*)d_in[4];
  const float* W1   = (const float*)d_in[5];
  const float* b1   = (const float*)d_in[6];
  const float* W2   = (const float*)d_in[7];
  const float* b2   = (const float*)d_in[8];
  const int*   iidx = (const int*)d_in[9];
  const int*   prawh= (const int*)d_in[10];
  const int*   praww= (const int*)d_in[11];
  float* out = (float*)d_out;

  auto align = [](size_t x){ return (x + 255) & ~(size_t)255; };
  size_t off = 0;
  size_t o_cent = off; off = align(off + (size_t)KIMG*CC*DD*4);
  size_t o_vidx = off; off = align(off + (size_t)KIMG*NTOK*4);
  size_t o_vcnt = off; off = align(off + (size_t)KIMG*4);
  size_t o_scal = off; off = align(off + (size_t)KIMG*CC*4*4);
  size_t o_h1   = off; off = align(off + (size_t)KIMG*CC*DD*4);
  size_t o_lbl  = off; off = align(off + (size_t)KIMG*NTOK*4);
  size_t o_fs   = off; off = align(off + (size_t)KIMG*TG*CC*DD*4);
  size_t o_sx   = off; off = align(off + (size_t)KIMG*NWV*CC*4);
  size_t o_sy   = off; off = align(off + (size_t)KIMG*NWV*CC*4);
  size_t o_cn   = off; off = align(off + (size_t)KIMG*NWV*CC*4);
  (void)ws_size;  // ~9.6 MB needed; prior rounds confirm ws_size is larger

  char* ws = (char*)d_ws;
  float* cent  = (float*)(ws + o_cent);
  int*   vidx  = (int*)  (ws + o_vidx);
  int*   vcnt  = (int*)  (ws + o_vcnt);
  float* scal  = (float*)(ws + o_scal);
  float* h1    = (float*)(ws + o_h1);
  int*   labels= (int*)  (ws + o_lbl);
  float* fsums = (float*)(ws + o_fs);
  float* sxg   = (float*)(ws + o_sx);
  float* syg   = (float*)(ws + o_sy);
  float* ocnt  = (float*)(ws + o_cn);

  compact_kernel<<<KIMG,256,0,stream>>>(mask, vidx, vcnt);
  init_kernel<<<KIMG,256,0,stream>>>(feat, boxes, Wp, bp, iidx, prawh, praww, cent);
  scalar_kernel<<<dim3(CC,KIMG),64,0,stream>>>(cent, Wp, bp, scal);
  for (int it=0; it<NITER; ++it){
    assign_kernel<<<dim3(GA,KIMG),512,0,stream>>>(feat, boxes, prawh, praww,
        cent, scal, vidx, vcnt, labels, sxg, syg, ocnt);
    sum_kernel<<<dim3(TG,3,KIMG),512,0,stream>>>(feat, vidx, vcnt, labels, fsums);
    update_kernel<<<(KIMG*CC*DD)/256,256,0,stream>>>(fsums, sxg, syg, ocnt, Wp, bp, cent);
    if (it < NITER-1)
      scalar_kernel<<<dim3(CC,KIMG),64,0,stream>>>(cent, Wp, bp, scal);
  }
  mlp1_kernel<<<dim3(3,KIMG),256,0,stream>>>(cent, W1, b1, h1);
  mlp2_kernel<<<dim3(3,KIMG),256,0,stream>>>(h1, W2, b2, out);
}